// Round 1
// baseline (5801.347 us; speedup 1.0000x reference)
//
#include <hip/hip_runtime.h>
#include <math.h>

#define BB 64
#define PP 196
#define SS 22
#define TT 21
#define VV 10000
#define EE 512
#define AA 512
#define UU 512
#define EC 2048

// d_out layout (floats): pred [B,T,V] | alpha [B,T,P] | seqs [B,S] | iter_lens [B] | order [B]
#define OUT_PRED  0
#define OUT_ALPHA (BB*TT*VV)
#define OUT_SEQ   (OUT_ALPHA + BB*TT*PP)
#define OUT_ILEN  (OUT_SEQ + BB*SS)
#define OUT_ORDER (OUT_ILEN + BB)

__device__ __forceinline__ float sigm(float x) { return 1.0f / (1.0f + expf(-x)); }

// ---------------------------------------------------------------------------
// Sort batch by descending length (stable), emit order/iter_lens/sorted seqs.
__global__ void k_sort(const int* __restrict__ lens, const int* __restrict__ seqs,
                       int* __restrict__ order, int* __restrict__ ilens,
                       float* __restrict__ out)
{
    __shared__ int ord_s[BB];
    int i = threadIdx.x;
    int li = lens[i];
    int rank = 0;
    for (int j = 0; j < BB; ++j) {
        int lj = lens[j];
        rank += (lj > li) || (lj == li && j < i);
    }
    ord_s[rank] = i;
    __syncthreads();
    int o = ord_s[i];
    order[i] = o;
    int il = lens[o] - 1;
    ilens[i] = il;
    for (int s = 0; s < SS; ++s)
        out[OUT_SEQ + i * SS + s] = (float)seqs[o * SS + s];
    out[OUT_ILEN + i] = (float)il;
    out[OUT_ORDER + i] = (float)o;
}

// Row-offset tables for the gathered GEMMs (att1 rows = sorted enc pixels,
// zemb rows = embedding rows of sorted tokens).
__global__ void k_rowoff(const int* __restrict__ order, const int* __restrict__ seqs,
                         int* __restrict__ roff1, int* __restrict__ roff2)
{
    int idx = blockIdx.x * 256 + threadIdx.x;
    if (idx < BB * PP) {
        int b = idx / PP, p = idx % PP;
        roff1[idx] = order[b] * (PP * EC) + p * EC;
    }
    if (idx < BB * TT) {
        int b = idx / TT, t = idx % TT;
        int tok = seqs[order[b] * SS + t];
        roff2[idx] = tok * EE;
    }
}

// mean over pixels of sorted enc -> meanE [B,ENC]
__global__ __launch_bounds__(256) void k_mean(const float* __restrict__ enc,
                                              const int* __restrict__ order,
                                              float* __restrict__ meanE)
{
    int idx = blockIdx.x * 256 + threadIdx.x;   // b*2048 + e
    int b = idx >> 11, e = idx & 2047;
    const float* base = enc + (size_t)order[b] * (PP * EC) + e;
    float s = 0.f;
    for (int p = 0; p < PP; ++p) s += base[p * EC];
    meanE[idx] = s * (1.0f / PP);
}

// ---------------------------------------------------------------------------
// Large tiled fp32 GEMM with gathered A rows: C[M,N] = A[roff] @ W + bias
// BM=BN=64, BK=16, 256 threads, 4x4 micro-tile per thread.
__global__ __launch_bounds__(256) void k_gemm_tile(
    const float* __restrict__ Abase, const int* __restrict__ roff,
    const float* __restrict__ W, const float* __restrict__ bias,
    float* __restrict__ C, int N, int K)
{
    __shared__ float As[16 * 68];   // [kk][m], padded stride 68
    __shared__ float Bs[16 * 64];   // [kk][n]
    int n0 = blockIdx.x * 64;
    int m0 = blockIdx.y * 64;
    int tid = threadIdx.x;
    int tr = tid >> 4, tc = tid & 15;
    float acc[4][4] = {};
    for (int k0 = 0; k0 < K; k0 += 16) {
        __syncthreads();
        #pragma unroll
        for (int q = 0; q < 4; ++q) {
            int idx = tid + q * 256;
            int m = idx >> 4, kk = idx & 15;
            As[kk * 68 + m] = Abase[(size_t)roff[m0 + m] + k0 + kk];
            int kb = idx >> 6, nn = idx & 63;
            Bs[kb * 64 + nn] = W[(size_t)(k0 + kb) * N + n0 + nn];
        }
        __syncthreads();
        #pragma unroll
        for (int kk = 0; kk < 16; ++kk) {
            float4 a4 = *(const float4*)&As[kk * 68 + tr * 4];
            float4 b4 = *(const float4*)&Bs[kk * 64 + tc * 4];
            acc[0][0] += a4.x * b4.x; acc[0][1] += a4.x * b4.y; acc[0][2] += a4.x * b4.z; acc[0][3] += a4.x * b4.w;
            acc[1][0] += a4.y * b4.x; acc[1][1] += a4.y * b4.y; acc[1][2] += a4.y * b4.z; acc[1][3] += a4.y * b4.w;
            acc[2][0] += a4.z * b4.x; acc[2][1] += a4.z * b4.y; acc[2][2] += a4.z * b4.z; acc[2][3] += a4.z * b4.w;
            acc[3][0] += a4.w * b4.x; acc[3][1] += a4.w * b4.y; acc[3][2] += a4.w * b4.z; acc[3][3] += a4.w * b4.w;
        }
    }
    #pragma unroll
    for (int i = 0; i < 4; ++i) {
        int m = m0 + tr * 4 + i;
        int n = n0 + tc * 4;
        float4 bv = bias ? *(const float4*)&bias[n] : make_float4(0.f, 0.f, 0.f, 0.f);
        float4 r;
        r.x = acc[i][0] + bv.x; r.y = acc[i][1] + bv.y;
        r.z = acc[i][2] + bv.z; r.w = acc[i][3] + bv.w;
        *(float4*)&C[(size_t)m * N + n] = r;
    }
}

// ---------------------------------------------------------------------------
// Skinny-M (M=64) GEMM with K-split + atomic accumulation.
// Supports two K-segments (x1/x2 with their own W) and two N-segments
// (Wa/Wb with separate outputs). Kc = 128. Targets must be pre-zeroed.
__global__ __launch_bounds__(256) void k_gemm64(
    const float* __restrict__ x1, const float* __restrict__ x2,
    const float* __restrict__ Wa1, const float* __restrict__ Wb1,
    const float* __restrict__ Wa2, const float* __restrict__ Wb2,
    int K1, int K2, int Na, int limA, int sA, int limB, int sB,
    float* __restrict__ Ca, int sCa, float* __restrict__ Cb, int sCb)
{
    __shared__ float xs[64 * 130];  // [b][k], padded stride 130 (bank-conflict-free)
    int n0 = blockIdx.x * 64;
    int kz = blockIdx.y;
    int nk1 = K1 >> 7;
    const float* xp; const float* Wa; const float* Wb; int k0, Kx;
    if (kz < nk1) { xp = x1; Wa = Wa1; Wb = Wb1; k0 = kz << 7; Kx = K1; }
    else          { xp = x2; Wa = Wa2; Wb = Wb2; k0 = (kz - nk1) << 7; Kx = K2; }

    for (int idx = threadIdx.x; idx < 64 * 128; idx += 256) {
        int b = idx >> 7, k = idx & 127;
        xs[b * 130 + k] = xp[(size_t)b * Kx + k0 + k];
    }
    __syncthreads();

    const float* W; int col0, stride, lim; float* C; int sC;
    if (n0 < Na) { W = Wa; col0 = n0;      stride = sA; lim = limA; C = Ca; sC = sCa; }
    else         { W = Wb; col0 = n0 - Na; stride = sB; lim = limB; C = Cb; sC = sCb; }

    int ng = threadIdx.x & 15, bg = threadIdx.x >> 4;
    int c0 = col0 + ng * 4;
    bool full = (c0 + 4 <= lim);
    const float* Wrow = W + (size_t)k0 * stride + c0;
    float acc[4][4] = {};
    for (int k = 0; k < 128; ++k) {
        float4 w;
        if (full) {
            w = *(const float4*)(Wrow + (size_t)k * stride);
        } else {
            w.x = (c0 + 0 < lim) ? Wrow[(size_t)k * stride + 0] : 0.f;
            w.y = (c0 + 1 < lim) ? Wrow[(size_t)k * stride + 1] : 0.f;
            w.z = (c0 + 2 < lim) ? Wrow[(size_t)k * stride + 2] : 0.f;
            w.w = (c0 + 3 < lim) ? Wrow[(size_t)k * stride + 3] : 0.f;
        }
        #pragma unroll
        for (int i = 0; i < 4; ++i) {
            float xv = xs[(bg * 4 + i) * 130 + k];
            acc[i][0] += xv * w.x; acc[i][1] += xv * w.y;
            acc[i][2] += xv * w.z; acc[i][3] += xv * w.w;
        }
    }
    #pragma unroll
    for (int i = 0; i < 4; ++i) {
        int b = bg * 4 + i;
        #pragma unroll
        for (int j = 0; j < 4; ++j) {
            int cc = c0 + j;
            if (cc < lim) atomicAdd(&C[(size_t)b * sC + cc], acc[i][j]);
        }
    }
}

// add init biases to h,c after atomic GEMM
__global__ void k_initbias(float* __restrict__ h, float* __restrict__ c,
                           const float* __restrict__ bm, const float* __restrict__ bc)
{
    int u = threadIdx.x; int b = blockIdx.x;
    h[b * UU + u] += bm[u];
    c[b * UU + u] += bc[u];
}

// e[b,p] = sum_a relu(att1 + att2 + b_att_gen) * W_att_full   (b_att_full dropped:
// constant shift cancels in softmax)
__global__ __launch_bounds__(256) void k_e(
    const float* __restrict__ att1, const float* __restrict__ att2r,
    const float* __restrict__ bgen, const float* __restrict__ Wf,
    float* __restrict__ eOut)
{
    int gid = blockIdx.x * 4 + (threadIdx.x >> 6);   // = b*196+p
    int lane = threadIdx.x & 63;
    int b = gid / PP;
    int a0 = lane * 8;
    const float4* A1 = (const float4*)(att1 + (size_t)gid * AA + a0);
    const float4* A2 = (const float4*)(att2r + b * AA + a0);
    const float4* BG = (const float4*)(bgen + a0);
    const float4* WF = (const float4*)(Wf + a0);
    float acc = 0.f;
    #pragma unroll
    for (int h = 0; h < 2; ++h) {
        float4 x = A1[h], y = A2[h], g = BG[h], w = WF[h];
        acc += fmaxf(x.x + y.x + g.x, 0.f) * w.x + fmaxf(x.y + y.y + g.y, 0.f) * w.y
             + fmaxf(x.z + y.z + g.z, 0.f) * w.z + fmaxf(x.w + y.w + g.w, 0.f) * w.w;
    }
    for (int s = 32; s; s >>= 1) acc += __shfl_down(acc, s);
    if (lane == 0) eOut[gid] = acc;
}

// softmax over pixels, masked alpha to output, awe = (alpha . enc) * sigmoid(beta),
// clears att2r/betar for next step's atomic GEMM.
__global__ __launch_bounds__(256) void k_alphaawe(
    const float* __restrict__ eBuf, const float* __restrict__ enc,
    const int* __restrict__ order, const int* __restrict__ ilens,
    float* __restrict__ att2r, float* __restrict__ betar,
    const float* __restrict__ bbeta, float* __restrict__ awe,
    float* __restrict__ out, int t)
{
    __shared__ float red[256];
    __shared__ float alpha_s[PP];
    int chunk = blockIdx.x;   // 0..7 (ENC/256)
    int b = blockIdx.y;
    int tid = threadIdx.x;
    float ev = (tid < PP) ? eBuf[b * PP + tid] : -1e30f;
    red[tid] = ev; __syncthreads();
    for (int s2 = 128; s2 >= 1; s2 >>= 1) {
        if (tid < s2) red[tid] = fmaxf(red[tid], red[tid + s2]);
        __syncthreads();
    }
    float mx = red[0]; __syncthreads();
    float ex = (tid < PP) ? expf(ev - mx) : 0.f;
    red[tid] = ex; __syncthreads();
    for (int s2 = 128; s2 >= 1; s2 >>= 1) {
        if (tid < s2) red[tid] += red[tid + s2];
        __syncthreads();
    }
    float inv = 1.0f / red[0];
    bool act = (t < ilens[b]);
    if (tid < PP) alpha_s[tid] = ex * inv;
    if (chunk == 0 && tid < PP)
        out[OUT_ALPHA + ((size_t)b * TT + t) * PP + tid] = act ? ex * inv : 0.f;
    if (chunk < 2) att2r[b * AA + chunk * 256 + tid] = 0.f;   // clear for next step
    __syncthreads();

    int e = chunk * 256 + tid;
    const float* ebase = enc + (size_t)order[b] * (PP * EC) + e;
    float s = 0.f;
    for (int p = 0; p < PP; ++p) s += alpha_s[p] * ebase[p * EC];
    float br = betar[b * EC + e];
    betar[b * EC + e] = 0.f;                                   // clear for next step
    awe[b * EC + e] = s * sigm(br + bbeta[e]);
}

// LSTM gates + masked state update; zeroes z for next step's atomic GEMM.
__global__ __launch_bounds__(256) void k_gates(
    float* __restrict__ z, const float* __restrict__ zemb, const float* __restrict__ blstm,
    float* __restrict__ h, float* __restrict__ c, const int* __restrict__ ilens, int t)
{
    int idx = blockIdx.x * 256 + threadIdx.x;   // b*512 + u
    int b = idx >> 9, u = idx & 511;
    const float* ze = zemb + ((size_t)b * TT + t) * EC;
    float zi = z[b * EC + u]        + ze[u]        + blstm[u];
    float zf = z[b * EC + u + 512]  + ze[u + 512]  + blstm[u + 512];
    float zg = z[b * EC + u + 1024] + ze[u + 1024] + blstm[u + 1024];
    float zo = z[b * EC + u + 1536] + ze[u + 1536] + blstm[u + 1536];
    z[b * EC + u] = 0.f; z[b * EC + u + 512] = 0.f;
    z[b * EC + u + 1024] = 0.f; z[b * EC + u + 1536] = 0.f;
    float cold = c[idx];
    float cn = sigm(zf) * cold + sigm(zi) * tanhf(zg);
    float hn = sigm(zo) * tanhf(cn);
    if (t < ilens[b]) { c[idx] = cn; h[idx] = hn; }
}

// vocab softmax from carry state logits; masked write; zeroes logits.
__global__ __launch_bounds__(1024) void k_pred(
    float* __restrict__ logits, const float* __restrict__ bout,
    const int* __restrict__ ilens, float* __restrict__ out, int t)
{
    __shared__ float red[1024];
    int b = blockIdx.x, tid = threadIdx.x;
    float mx = -1e30f;
    for (int v = tid; v < VV; v += 1024) mx = fmaxf(mx, logits[b * VV + v] + bout[v]);
    red[tid] = mx; __syncthreads();
    for (int s2 = 512; s2 >= 1; s2 >>= 1) {
        if (tid < s2) red[tid] = fmaxf(red[tid], red[tid + s2]);
        __syncthreads();
    }
    mx = red[0]; __syncthreads();
    float sm = 0.f;
    for (int v = tid; v < VV; v += 1024) sm += expf(logits[b * VV + v] + bout[v] - mx);
    red[tid] = sm; __syncthreads();
    for (int s2 = 512; s2 >= 1; s2 >>= 1) {
        if (tid < s2) red[tid] += red[tid + s2];
        __syncthreads();
    }
    float inv = 1.0f / red[0];
    bool act = t < ilens[b];
    float* po = out + OUT_PRED + ((size_t)b * TT + t) * VV;
    for (int v = tid; v < VV; v += 1024) {
        float pv = act ? expf(logits[b * VV + v] + bout[v] - mx) * inv : 0.f;
        po[v] = pv;
        logits[b * VV + v] = 0.f;   // clear for next step
    }
}

// ---------------------------------------------------------------------------
extern "C" void kernel_launch(void* const* d_in, const int* in_sizes, int n_in,
                              void* d_out, int out_size, void* d_ws, size_t ws_size,
                              hipStream_t stream)
{
    (void)in_sizes; (void)n_in; (void)out_size; (void)ws_size;
    const float* enc  = (const float*)d_in[0];
    const int*   seqs = (const int*)d_in[1];
    const int*   lens = (const int*)d_in[2];
    const float* embT = (const float*)d_in[3];
    const float* W_ae = (const float*)d_in[4];
    const float* b_ae = (const float*)d_in[5];
    const float* W_ag = (const float*)d_in[6];
    const float* b_ag = (const float*)d_in[7];
    const float* W_af = (const float*)d_in[8];
    // d_in[9] = b_att_full: constant shift before softmax -> cancels, unused.
    const float* W_x  = (const float*)d_in[10];
    const float* W_h  = (const float*)d_in[11];
    const float* b_l  = (const float*)d_in[12];
    const float* W_im = (const float*)d_in[13];
    const float* b_im = (const float*)d_in[14];
    const float* W_ic = (const float*)d_in[15];
    const float* b_ic = (const float*)d_in[16];
    const float* W_b  = (const float*)d_in[17];
    const float* b_b  = (const float*)d_in[18];
    const float* W_o  = (const float*)d_in[19];
    const float* b_o  = (const float*)d_in[20];
    float* out = (float*)d_out;

    float* ws    = (float*)d_ws;
    float* att1  = ws;                       // [B*P, A]      6422528
    float* zemb  = att1 + 6422528;           // [B*T, 4U]     2752512
    float* meanE = zemb + 2752512;           // [B, ENC]      131072
    float* eBuf  = meanE + 131072;           // [B, P]        12544
    float* aweB  = eBuf + 12544;             // [B, ENC]      131072
    float* att2r = aweB + 131072;            // [B, A]        32768   (zero region ->)
    float* betar = att2r + 32768;            // [B, ENC]      131072
    float* hB    = betar + 131072;           // [B, U]        32768
    float* cB    = hB + 32768;               // [B, U]        32768
    float* zB    = cB + 32768;               // [B, 4U]       131072
    float* logit = zB + 131072;              // [B, V]        640000  (<- zero region)
    int* order = (int*)(logit + 640000);
    int* ilens = order + 64;
    int* roff1 = ilens + 64;                 // 12544
    int* roff2 = roff1 + 12544;              // 1344

    // zero all atomic-accumulation targets once; step kernels re-zero in a ring
    hipMemsetAsync(att2r, 0,
                   (size_t)(32768 + 131072 + 32768 + 32768 + 131072 + 640000) * 4, stream);

    k_sort<<<1, 64, 0, stream>>>(lens, seqs, order, ilens, out);
    k_rowoff<<<49, 256, 0, stream>>>(order, seqs, roff1, roff2);
    k_mean<<<512, 256, 0, stream>>>(enc, order, meanE);

    // h = meanE@W_init_m, c = meanE@W_init_c (atomic), then + biases
    k_gemm64<<<dim3(16, 16), 256, 0, stream>>>(
        meanE, nullptr, W_im, W_ic, nullptr, nullptr,
        2048, 0, 512, 512, 512, 512, 512, hB, 512, cB, 512);
    k_initbias<<<64, 512, 0, stream>>>(hB, cB, b_im, b_ic);

    // att1 = sorted_enc @ W_att_enc + b_att_enc   [12544 x 512], K=2048
    k_gemm_tile<<<dim3(8, 196), 256, 0, stream>>>(enc, roff1, W_ae, b_ae, att1, 512, 2048);
    // zemb = emb(sorted tokens) @ W_x[0:512]      [1344 x 2048], K=512
    k_gemm_tile<<<dim3(32, 21), 256, 0, stream>>>(embT, roff2, W_x, nullptr, zemb, 2048, 512);

    for (int t = 0; t < TT; ++t) {
        // att2 = c@W_att_gen ; beta_logit = c@W_beta  (column-segmented, atomic)
        k_gemm64<<<dim3(40, 4), 256, 0, stream>>>(
            cB, nullptr, W_ag, W_b, nullptr, nullptr,
            512, 0, 512, 512, 512, 2048, 2048, att2r, 512, betar, 2048);
        k_e<<<3136, 256, 0, stream>>>(att1, att2r, b_ag, W_af, eBuf);
        k_alphaawe<<<dim3(8, 64), 256, 0, stream>>>(
            eBuf, enc, order, ilens, att2r, betar, b_b, aweB, out, t);
        // z += awe@W_x[512:] + h@W_h   (K-segmented, atomic; emb part precomputed)
        k_gemm64<<<dim3(32, 20), 256, 0, stream>>>(
            aweB, hB, W_x + (size_t)512 * 2048, nullptr, W_h, nullptr,
            2048, 512, 2048, 2048, 2048, 0, 0, zB, 2048, nullptr, 0);
        k_gates<<<128, 256, 0, stream>>>(zB, zemb, b_l, hB, cB, ilens, t);
        // logits = c2 @ W_out (atomic)
        k_gemm64<<<dim3(157, 4), 256, 0, stream>>>(
            cB, nullptr, W_o, nullptr, nullptr, nullptr,
            512, 0, 10048, 10000, 10000, 0, 0, logit, 10000, nullptr, 0);
        k_pred<<<64, 1024, 0, stream>>>(logit, b_o, ilens, out, t);
    }
}

// Round 2
// 4914.236 us; speedup vs baseline: 1.1805x; 1.1805x over previous
//
#include <hip/hip_runtime.h>
#include <math.h>

#define BB 64
#define PP 196
#define SS 22
#define TT 21
#define VV 10000
#define EE 512
#define AA 512
#define UU 512
#define EC 2048

// d_out layout (floats): pred [B,T,V] | alpha [B,T,P] | seqs [B,S] | iter_lens [B] | order [B]
#define OUT_PRED  0
#define OUT_ALPHA (BB*TT*VV)
#define OUT_SEQ   (OUT_ALPHA + BB*TT*PP)
#define OUT_ILEN  (OUT_SEQ + BB*SS)
#define OUT_ORDER (OUT_ILEN + BB)

__device__ __forceinline__ float sigm(float x) { return 1.0f / (1.0f + expf(-x)); }

// ---------------------------------------------------------------------------
__global__ void k_sort(const int* __restrict__ lens, const int* __restrict__ seqs,
                       int* __restrict__ order, int* __restrict__ ilens,
                       float* __restrict__ out)
{
    __shared__ int ord_s[BB];
    int i = threadIdx.x;
    int li = lens[i];
    int rank = 0;
    for (int j = 0; j < BB; ++j) {
        int lj = lens[j];
        rank += (lj > li) || (lj == li && j < i);
    }
    ord_s[rank] = i;
    __syncthreads();
    int o = ord_s[i];
    order[i] = o;
    int il = lens[o] - 1;
    ilens[i] = il;
    for (int s = 0; s < SS; ++s)
        out[OUT_SEQ + i * SS + s] = (float)seqs[o * SS + s];
    out[OUT_ILEN + i] = (float)il;
    out[OUT_ORDER + i] = (float)o;
}

__global__ void k_rowoff(const int* __restrict__ order, const int* __restrict__ seqs,
                         int* __restrict__ roff1, int* __restrict__ roff2)
{
    int idx = blockIdx.x * 256 + threadIdx.x;
    if (idx < BB * PP) {
        int b = idx / PP, p = idx % PP;
        roff1[idx] = order[b] * (PP * EC) + p * EC;
    }
    if (idx < BB * TT) {
        int b = idx / TT, t = idx % TT;
        int tok = seqs[order[b] * SS + t];
        roff2[idx] = tok * EE;
    }
}

__global__ __launch_bounds__(256) void k_mean(const float* __restrict__ enc,
                                              const int* __restrict__ order,
                                              float* __restrict__ meanE)
{
    int idx = blockIdx.x * 256 + threadIdx.x;   // b*2048 + e
    int b = idx >> 11, e = idx & 2047;
    const float* base = enc + (size_t)order[b] * (PP * EC) + e;
    float s = 0.f;
    for (int p = 0; p < PP; ++p) s += base[p * EC];
    meanE[idx] = s * (1.0f / PP);
}

// ---------------------------------------------------------------------------
// fp32 tile GEMM, gathered A rows: C[M,N] = A[roff] @ W (+bias)
// BM=128, BN=64, BK=16, 256 threads, 8x4 micro-tile, reg-prefetch double buffer,
// XCD-chunked block swizzle (consecutive logical tiles share A-panels per XCD).
__global__ __launch_bounds__(256) void k_gemm_tile128(
    const float* __restrict__ Abase, const int* __restrict__ roff,
    const float* __restrict__ W, const float* __restrict__ bias,
    float* __restrict__ C, int M, int N, int K)
{
    __shared__ float As[16][128];   // [kk][m] transposed
    __shared__ float Bs[16][64];    // [kk][n]
    int nwg = gridDim.x;
    int bid = blockIdx.x;
    int q = nwg >> 3, r = nwg & 7;
    int x = bid & 7, y = bid >> 3;
    int lbid = (x < r ? x * (q + 1) : r * (q + 1) + (x - r) * q) + y;
    int ntn = N >> 6;
    int mt = lbid / ntn, nt = lbid % ntn;

    int tid = threadIdx.x;
    int arow = tid >> 1, akq = (tid & 1) * 8;
    int brow = tid >> 4, bc4 = (tid & 15) * 4;
    int am = mt * 128 + arow; if (am > M - 1) am = M - 1;
    const float* aptr = Abase + (size_t)roff[am] + akq;
    const float* bptr = W + (size_t)brow * N + nt * 64 + bc4;
    float4 a0 = *(const float4*)(aptr);
    float4 a1 = *(const float4*)(aptr + 4);
    float4 b0 = *(const float4*)(bptr);
    float acc[8][4] = {};
    int tr8 = (tid >> 4) * 8, tc4 = (tid & 15) * 4;

    for (int k0 = 0; k0 < K; k0 += 16) {
        float* ac = &As[akq][arow];
        ac[0]   = a0.x; ac[128] = a0.y; ac[256] = a0.z; ac[384] = a0.w;
        ac[512] = a1.x; ac[640] = a1.y; ac[768] = a1.z; ac[896] = a1.w;
        *(float4*)&Bs[brow][bc4] = b0;
        __syncthreads();
        if (k0 + 16 < K) {
            a0 = *(const float4*)(aptr + k0 + 16);
            a1 = *(const float4*)(aptr + k0 + 20);
            b0 = *(const float4*)(bptr + (size_t)(k0 + 16) * N);
        }
        #pragma unroll
        for (int kk = 0; kk < 16; ++kk) {
            float4 aA = *(float4*)&As[kk][tr8];
            float4 aB = *(float4*)&As[kk][tr8 + 4];
            float4 bb = *(float4*)&Bs[kk][tc4];
            float av[8] = {aA.x, aA.y, aA.z, aA.w, aB.x, aB.y, aB.z, aB.w};
            float bv[4] = {bb.x, bb.y, bb.z, bb.w};
            #pragma unroll
            for (int i = 0; i < 8; ++i)
                #pragma unroll
                for (int j = 0; j < 4; ++j)
                    acc[i][j] += av[i] * bv[j];
        }
        __syncthreads();
    }
    float4 bvv = make_float4(0.f, 0.f, 0.f, 0.f);
    if (bias) bvv = *(const float4*)&bias[nt * 64 + tc4];
    #pragma unroll
    for (int i = 0; i < 8; ++i) {
        int m = mt * 128 + tr8 + i;
        if (m < M) {
            float4 rr;
            rr.x = acc[i][0] + bvv.x; rr.y = acc[i][1] + bvv.y;
            rr.z = acc[i][2] + bvv.z; rr.w = acc[i][3] + bvv.w;
            *(float4*)&C[(size_t)m * N + nt * 64 + tc4] = rr;
        }
    }
}

// ---------------------------------------------------------------------------
// Skinny-M (M=64) GEMM with K-split + atomic accumulation (targets pre-zeroed).
__global__ __launch_bounds__(256) void k_gemm64(
    const float* __restrict__ x1, const float* __restrict__ x2,
    const float* __restrict__ Wa1, const float* __restrict__ Wb1,
    const float* __restrict__ Wa2, const float* __restrict__ Wb2,
    int K1, int K2, int Na, int limA, int sA, int limB, int sB,
    float* __restrict__ Ca, int sCa, float* __restrict__ Cb, int sCb)
{
    __shared__ float xs[64 * 130];
    int n0 = blockIdx.x * 64;
    int kz = blockIdx.y;
    int nk1 = K1 >> 7;
    const float* xp; const float* Wa; const float* Wb; int k0, Kx;
    if (kz < nk1) { xp = x1; Wa = Wa1; Wb = Wb1; k0 = kz << 7; Kx = K1; }
    else          { xp = x2; Wa = Wa2; Wb = Wb2; k0 = (kz - nk1) << 7; Kx = K2; }

    for (int idx = threadIdx.x; idx < 64 * 128; idx += 256) {
        int b = idx >> 7, k = idx & 127;
        xs[b * 130 + k] = xp[(size_t)b * Kx + k0 + k];
    }
    __syncthreads();

    const float* W; int col0, stride, lim; float* C; int sC;
    if (n0 < Na) { W = Wa; col0 = n0;      stride = sA; lim = limA; C = Ca; sC = sCa; }
    else         { W = Wb; col0 = n0 - Na; stride = sB; lim = limB; C = Cb; sC = sCb; }

    int ng = threadIdx.x & 15, bg = threadIdx.x >> 4;
    int c0 = col0 + ng * 4;
    bool full = (c0 + 4 <= lim);
    const float* Wrow = W + (size_t)k0 * stride + c0;
    float acc[4][4] = {};
    #pragma unroll 8
    for (int k = 0; k < 128; ++k) {
        float4 w;
        if (full) {
            w = *(const float4*)(Wrow + (size_t)k * stride);
        } else {
            w.x = (c0 + 0 < lim) ? Wrow[(size_t)k * stride + 0] : 0.f;
            w.y = (c0 + 1 < lim) ? Wrow[(size_t)k * stride + 1] : 0.f;
            w.z = (c0 + 2 < lim) ? Wrow[(size_t)k * stride + 2] : 0.f;
            w.w = (c0 + 3 < lim) ? Wrow[(size_t)k * stride + 3] : 0.f;
        }
        #pragma unroll
        for (int i = 0; i < 4; ++i) {
            float xv = xs[(bg * 4 + i) * 130 + k];
            acc[i][0] += xv * w.x; acc[i][1] += xv * w.y;
            acc[i][2] += xv * w.z; acc[i][3] += xv * w.w;
        }
    }
    #pragma unroll
    for (int i = 0; i < 4; ++i) {
        int b = bg * 4 + i;
        #pragma unroll
        for (int j = 0; j < 4; ++j) {
            int cc = c0 + j;
            if (cc < lim) atomicAdd(&C[(size_t)b * sC + cc], acc[i][j]);
        }
    }
}

__global__ void k_initbias(float* __restrict__ h, float* __restrict__ c,
                           const float* __restrict__ bm, const float* __restrict__ bc)
{
    int u = threadIdx.x; int b = blockIdx.x;
    h[b * UU + u] += bm[u];
    c[b * UU + u] += bc[u];
}

// ---------------------------------------------------------------------------
// e + softmax fused, one block per active batch row. Writes alpha to out and ws.
__global__ __launch_bounds__(512) void k_score(
    const float* __restrict__ att1, const float* __restrict__ att2r,
    const float* __restrict__ bgen, const float* __restrict__ Wf,
    const int* __restrict__ ilens, float* __restrict__ alphaS,
    float* __restrict__ out, int t)
{
    int b = blockIdx.x;
    if (t >= ilens[b]) return;            // inactive prefix row: out pre-zeroed
    __shared__ float att2g[AA], wfs[AA], es[PP], red[512];
    int tid = threadIdx.x;
    if (tid < AA) { att2g[tid] = att2r[b * AA + tid] + bgen[tid]; wfs[tid] = Wf[tid]; }
    __syncthreads();
    int wv = tid >> 6, lane = tid & 63;
    int a0 = lane * 8;
    float4 g0 = *(float4*)&att2g[a0], g1 = *(float4*)&att2g[a0 + 4];
    float4 w0 = *(float4*)&wfs[a0],  w1 = *(float4*)&wfs[a0 + 4];
    for (int p = wv; p < PP; p += 8) {
        const float4* A1 = (const float4*)(att1 + ((size_t)b * PP + p) * AA + a0);
        float4 x0 = A1[0], x1 = A1[1];
        float acc = fmaxf(x0.x + g0.x, 0.f) * w0.x + fmaxf(x0.y + g0.y, 0.f) * w0.y
                  + fmaxf(x0.z + g0.z, 0.f) * w0.z + fmaxf(x0.w + g0.w, 0.f) * w0.w
                  + fmaxf(x1.x + g1.x, 0.f) * w1.x + fmaxf(x1.y + g1.y, 0.f) * w1.y
                  + fmaxf(x1.z + g1.z, 0.f) * w1.z + fmaxf(x1.w + g1.w, 0.f) * w1.w;
        #pragma unroll
        for (int s = 32; s; s >>= 1) acc += __shfl_down(acc, s);
        if (lane == 0) es[p] = acc;
    }
    __syncthreads();
    float ev = (tid < PP) ? es[tid] : -1e30f;
    red[tid] = ev; __syncthreads();
    for (int s = 256; s >= 1; s >>= 1) {
        if (tid < s) red[tid] = fmaxf(red[tid], red[tid + s]);
        __syncthreads();
    }
    float mx = red[0]; __syncthreads();
    float ex = (tid < PP) ? expf(ev - mx) : 0.f;
    red[tid] = ex; __syncthreads();
    for (int s = 256; s >= 1; s >>= 1) {
        if (tid < s) red[tid] += red[tid + s];
        __syncthreads();
    }
    float inv = 1.0f / red[0];
    if (tid < PP) {
        float al = ex * inv;
        alphaS[b * PP + tid] = al;
        out[OUT_ALPHA + ((size_t)b * TT + t) * PP + tid] = al;
    }
}

// awe = (alpha . enc) * sigmoid(beta); clears att2r/betar for next step.
__global__ __launch_bounds__(256) void k_awe(
    const float* __restrict__ alphaS, const float* __restrict__ enc,
    const int* __restrict__ order, const int* __restrict__ ilens,
    float* __restrict__ att2r, float* __restrict__ betar,
    const float* __restrict__ bbeta, float* __restrict__ awe, int t)
{
    int b = blockIdx.y;
    if (t >= ilens[b]) return;            // stale awe/att2r/betar never consumed
    int chunk = blockIdx.x, tid = threadIdx.x;
    __shared__ float al[PP];
    if (tid < PP) al[tid] = alphaS[b * PP + tid];
    if (chunk < 2) att2r[b * AA + chunk * 256 + tid] = 0.f;
    __syncthreads();
    int e = chunk * 256 + tid;
    const float* ebase = enc + (size_t)order[b] * (PP * EC) + e;
    float s = 0.f;
    #pragma unroll 4
    for (int p = 0; p < PP; ++p) s += al[p] * ebase[(size_t)p * EC];
    float br = betar[b * EC + e];
    betar[b * EC + e] = 0.f;
    awe[b * EC + e] = s * sigm(br + bbeta[e]);
}

__global__ __launch_bounds__(256) void k_gates(
    float* __restrict__ z, const float* __restrict__ zemb, const float* __restrict__ blstm,
    float* __restrict__ h, float* __restrict__ c, const int* __restrict__ ilens, int t)
{
    int idx = blockIdx.x * 256 + threadIdx.x;   // b*512 + u
    int b = idx >> 9, u = idx & 511;
    const float* ze = zemb + ((size_t)b * TT + t) * EC;
    float zi = z[b * EC + u]         + ze[u]         + blstm[u];
    float zf = z[b * EC + u + 512]   + ze[u + 512]   + blstm[u + 512];
    float zg = z[b * EC + u + 1024]  + ze[u + 1024]  + blstm[u + 1024];
    float zo = z[b * EC + u + 1536]  + ze[u + 1536]  + blstm[u + 1536];
    z[b * EC + u] = 0.f; z[b * EC + u + 512] = 0.f;
    z[b * EC + u + 1024] = 0.f; z[b * EC + u + 1536] = 0.f;
    float cold = c[idx];
    float cn = sigm(zf) * cold + sigm(zi) * tanhf(zg);
    float hn = sigm(zo) * tanhf(cn);
    if (t < ilens[b]) { c[idx] = cn; h[idx] = hn; }
}

// vocab softmax; logits loaded once into registers; active rows only.
__global__ __launch_bounds__(1024) void k_pred(
    float* __restrict__ logits, const float* __restrict__ bout,
    const int* __restrict__ ilens, float* __restrict__ out, int t)
{
    int b = blockIdx.x;
    if (t >= ilens[b]) return;            // out pre-zeroed; stale logits never read
    __shared__ float red[16];
    int tid = threadIdx.x;
    int lane = tid & 63, wv = tid >> 6;
    float* lb = logits + (size_t)b * VV;
    float v[10];
    #pragma unroll
    for (int i = 0; i < 10; ++i) {
        int idx = tid + i * 1024;
        v[i] = (idx < VV) ? lb[idx] + bout[idx] : -1e30f;
    }
    float mx = v[0];
    #pragma unroll
    for (int i = 1; i < 10; ++i) mx = fmaxf(mx, v[i]);
    #pragma unroll
    for (int s = 32; s; s >>= 1) mx = fmaxf(mx, __shfl_xor(mx, s));
    if (lane == 0) red[wv] = mx;
    __syncthreads();
    if (tid == 0) {
        float m2 = red[0];
        for (int i = 1; i < 16; ++i) m2 = fmaxf(m2, red[i]);
        red[0] = m2;
    }
    __syncthreads();
    mx = red[0];
    __syncthreads();
    float sm = 0.f;
    #pragma unroll
    for (int i = 0; i < 10; ++i) {
        int idx = tid + i * 1024;
        float e = (idx < VV) ? expf(v[i] - mx) : 0.f;
        v[i] = e; sm += e;
    }
    #pragma unroll
    for (int s = 32; s; s >>= 1) sm += __shfl_xor(sm, s);
    if (lane == 0) red[wv] = sm;
    __syncthreads();
    if (tid == 0) {
        float s2 = 0.f;
        for (int i = 0; i < 16; ++i) s2 += red[i];
        red[0] = s2;
    }
    __syncthreads();
    float inv = 1.0f / red[0];
    float* po = out + OUT_PRED + ((size_t)b * TT + t) * VV;
    #pragma unroll
    for (int i = 0; i < 10; ++i) {
        int idx = tid + i * 1024;
        if (idx < VV) { po[idx] = v[i] * inv; lb[idx] = 0.f; }
    }
}

// ---------------------------------------------------------------------------
extern "C" void kernel_launch(void* const* d_in, const int* in_sizes, int n_in,
                              void* d_out, int out_size, void* d_ws, size_t ws_size,
                              hipStream_t stream)
{
    (void)in_sizes; (void)n_in; (void)out_size; (void)ws_size;
    const float* enc  = (const float*)d_in[0];
    const int*   seqs = (const int*)d_in[1];
    const int*   lens = (const int*)d_in[2];
    const float* embT = (const float*)d_in[3];
    const float* W_ae = (const float*)d_in[4];
    const float* b_ae = (const float*)d_in[5];
    const float* W_ag = (const float*)d_in[6];
    const float* b_ag = (const float*)d_in[7];
    const float* W_af = (const float*)d_in[8];
    // d_in[9] = b_att_full: constant pre-softmax shift, cancels.
    const float* W_x  = (const float*)d_in[10];
    const float* W_h  = (const float*)d_in[11];
    const float* b_l  = (const float*)d_in[12];
    const float* W_im = (const float*)d_in[13];
    const float* b_im = (const float*)d_in[14];
    const float* W_ic = (const float*)d_in[15];
    const float* b_ic = (const float*)d_in[16];
    const float* W_b  = (const float*)d_in[17];
    const float* b_b  = (const float*)d_in[18];
    const float* W_o  = (const float*)d_in[19];
    const float* b_o  = (const float*)d_in[20];
    float* out = (float*)d_out;

    float* ws     = (float*)d_ws;
    float* att1   = ws;                      // [B*P, A]   6422528
    float* zemb   = att1 + 6422528;          // [B*T, 4U]  2752512
    float* meanE  = zemb + 2752512;          // [B, ENC]   131072
    float* alphaS = meanE + 131072;          // [B, P]     12544
    float* aweB   = alphaS + 12544;          // [B, ENC]   131072
    float* att2r  = aweB + 131072;           // [B, A]     32768  (zero region ->)
    float* betar  = att2r + 32768;           // [B, ENC]   131072
    float* hB     = betar + 131072;          // [B, U]     32768
    float* cB     = hB + 32768;              // [B, U]     32768
    float* zB     = cB + 32768;              // [B, 4U]    131072
    float* logit  = zB + 131072;             // [B, V]     640000 (<- zero region)
    int* order = (int*)(logit + 640000);
    int* ilens = order + 64;
    int* roff1 = ilens + 64;                 // 12544
    int* roff2 = roff1 + 12544;              // 1344

    // masked outputs default to 0 (inactive rows are never written)
    hipMemsetAsync(out, 0, (size_t)OUT_SEQ * 4, stream);
    // atomic-accumulation targets zeroed once; step kernels re-zero in a ring
    hipMemsetAsync(att2r, 0,
                   (size_t)(32768 + 131072 + 32768 + 32768 + 131072 + 640000) * 4, stream);

    k_sort<<<1, 64, 0, stream>>>(lens, seqs, order, ilens, out);
    k_rowoff<<<49, 256, 0, stream>>>(order, seqs, roff1, roff2);
    k_mean<<<512, 256, 0, stream>>>(enc, order, meanE);

    k_gemm64<<<dim3(16, 16), 256, 0, stream>>>(
        meanE, nullptr, W_im, W_ic, nullptr, nullptr,
        2048, 0, 512, 512, 512, 512, 512, hB, 512, cB, 512);
    k_initbias<<<64, 512, 0, stream>>>(hB, cB, b_im, b_ic);

    // att1 = sorted_enc @ W_att_enc + b_att_enc   [12544 x 512], K=2048
    k_gemm_tile128<<<98 * 8, 256, 0, stream>>>(enc, roff1, W_ae, b_ae, att1, 12544, 512, 2048);
    // zemb = emb(sorted tokens) @ W_x[0:512]      [1344 x 2048], K=512
    k_gemm_tile128<<<11 * 32, 256, 0, stream>>>(embT, roff2, W_x, nullptr, zemb, 1344, 2048, 512);

    for (int t = 0; t < TT; ++t) {
        k_gemm64<<<dim3(40, 4), 256, 0, stream>>>(
            cB, nullptr, W_ag, W_b, nullptr, nullptr,
            512, 0, 512, 512, 512, 2048, 2048, att2r, 512, betar, 2048);
        k_score<<<64, 512, 0, stream>>>(att1, att2r, b_ag, W_af, ilens, alphaS, out, t);
        k_awe<<<dim3(8, 64), 256, 0, stream>>>(
            alphaS, enc, order, ilens, att2r, betar, b_b, aweB, t);
        k_gemm64<<<dim3(32, 20), 256, 0, stream>>>(
            aweB, hB, W_x + (size_t)512 * 2048, nullptr, W_h, nullptr,
            2048, 512, 2048, 2048, 2048, 0, 0, zB, 2048, nullptr, 0);
        k_gates<<<128, 256, 0, stream>>>(zB, zemb, b_l, hB, cB, ilens, t);
        k_gemm64<<<dim3(157, 4), 256, 0, stream>>>(
            cB, nullptr, W_o, nullptr, nullptr, nullptr,
            512, 0, 10048, 10000, 10000, 0, 0, logit, 10000, nullptr, 0);
        k_pred<<<64, 1024, 0, stream>>>(logit, b_o, ilens, out, t);
    }
}

// Round 4
// 3729.055 us; speedup vs baseline: 1.5557x; 1.3178x over previous
//
#include <hip/hip_runtime.h>
#include <math.h>

#define BB 64
#define PP 196
#define SS 22
#define TT 21
#define VV 10000
#define EE 512
#define AA 512
#define UU 512
#define EC 2048

// d_out layout (floats): pred [B,T,V] | alpha [B,T,P] | seqs [B,S] | iter_lens [B] | order [B]
#define OUT_PRED  0
#define OUT_ALPHA (BB*TT*VV)
#define OUT_SEQ   (OUT_ALPHA + BB*TT*PP)
#define OUT_ILEN  (OUT_SEQ + BB*SS)
#define OUT_ORDER (OUT_ILEN + BB)

__device__ __forceinline__ float sigm(float x) { return 1.0f / (1.0f + expf(-x)); }

// ---------------------------------------------------------------------------
__global__ void k_sort(const int* __restrict__ lens, const int* __restrict__ seqs,
                       int* __restrict__ order, int* __restrict__ ilens,
                       float* __restrict__ out)
{
    __shared__ int ord_s[BB];
    int i = threadIdx.x;
    int li = lens[i];
    int rank = 0;
    for (int j = 0; j < BB; ++j) {
        int lj = lens[j];
        rank += (lj > li) || (lj == li && j < i);
    }
    ord_s[rank] = i;
    __syncthreads();
    int o = ord_s[i];
    order[i] = o;
    int il = lens[o] - 1;
    ilens[i] = il;
    for (int s = 0; s < SS; ++s)
        out[OUT_SEQ + i * SS + s] = (float)seqs[o * SS + s];
    out[OUT_ILEN + i] = (float)il;
    out[OUT_ORDER + i] = (float)o;
}

__global__ void k_rowoff(const int* __restrict__ order, const int* __restrict__ seqs,
                         int* __restrict__ roff1, int* __restrict__ roff2)
{
    int idx = blockIdx.x * 256 + threadIdx.x;
    if (idx < BB * PP) {
        int b = idx / PP, p = idx % PP;
        roff1[idx] = order[b] * (PP * EC) + p * EC;
    }
    if (idx < BB * TT) {
        int b = idx / TT, t = idx % TT;
        int tok = seqs[order[b] * SS + t];
        roff2[idx] = tok * EE;
    }
}

__global__ __launch_bounds__(256) void k_mean(const float* __restrict__ enc,
                                              const int* __restrict__ order,
                                              float* __restrict__ meanE)
{
    int idx = blockIdx.x * 256 + threadIdx.x;   // b*2048 + e
    int b = idx >> 11, e = idx & 2047;
    const float* base = enc + (size_t)order[b] * (PP * EC) + e;
    float s = 0.f;
    for (int p = 0; p < PP; ++p) s += base[p * EC];
    meanE[idx] = s * (1.0f / PP);
}

// ---------------------------------------------------------------------------
// fp32 tile GEMM, gathered A rows: C[M,N] = A[roff] @ W (+bias)
// BM=BN=128, BK=16, 256 threads, 8x8 micro-tile (split 4+4 at stride 64),
// reg-prefetch double buffer, XCD-chunked block swizzle.
__global__ __launch_bounds__(256) void k_gemm_tile(
    const float* __restrict__ Abase, const int* __restrict__ roff,
    const float* __restrict__ W, const float* __restrict__ bias,
    float* __restrict__ C, int M, int N, int K)
{
    __shared__ float As[16][128];
    __shared__ float Bs[16][128];
    int nwg = gridDim.x, bid = blockIdx.x;
    int q = nwg >> 3, r = nwg & 7;
    int x = bid & 7, y = bid >> 3;
    int lbid = (x < r ? x * (q + 1) : r * (q + 1) + (x - r) * q) + y;
    int ntn = N >> 7;
    int mt = lbid / ntn, nt = lbid % ntn;
    int tid = threadIdx.x;

    int arow = tid >> 1, akq = (tid & 1) * 8;
    int am = mt * 128 + arow; if (am > M - 1) am = M - 1;
    const float* aptr = Abase + (size_t)roff[am] + akq;
    int bkr = tid >> 5, bc4 = (tid & 31) * 4;
    const float* bptr = W + (size_t)bkr * N + nt * 128 + bc4;

    float4 a0 = *(const float4*)(aptr);
    float4 a1 = *(const float4*)(aptr + 4);
    float4 b0 = *(const float4*)(bptr);
    float4 b1 = *(const float4*)(bptr + (size_t)8 * N);

    int tr = tid >> 4, tc = tid & 15;
    float acc[8][8] = {};

    for (int k0 = 0; k0 < K; k0 += 16) {
        float* ac = &As[akq][arow];
        ac[0]   = a0.x; ac[128] = a0.y; ac[256] = a0.z; ac[384] = a0.w;
        ac[512] = a1.x; ac[640] = a1.y; ac[768] = a1.z; ac[896] = a1.w;
        *(float4*)&Bs[bkr][bc4] = b0;
        *(float4*)&Bs[bkr + 8][bc4] = b1;
        __syncthreads();
        if (k0 + 16 < K) {
            a0 = *(const float4*)(aptr + k0 + 16);
            a1 = *(const float4*)(aptr + k0 + 20);
            b0 = *(const float4*)(bptr + (size_t)(k0 + 16) * N);
            b1 = *(const float4*)(bptr + (size_t)(k0 + 24) * N);
        }
        #pragma unroll
        for (int kk = 0; kk < 16; ++kk) {
            float4 aL = *(float4*)&As[kk][tr * 4];
            float4 aH = *(float4*)&As[kk][tr * 4 + 64];
            float4 bL = *(float4*)&Bs[kk][tc * 4];
            float4 bH = *(float4*)&Bs[kk][tc * 4 + 64];
            float av[8] = {aL.x, aL.y, aL.z, aL.w, aH.x, aH.y, aH.z, aH.w};
            float bv[8] = {bL.x, bL.y, bL.z, bL.w, bH.x, bH.y, bH.z, bH.w};
            #pragma unroll
            for (int i = 0; i < 8; ++i)
                #pragma unroll
                for (int j = 0; j < 8; ++j)
                    acc[i][j] += av[i] * bv[j];
        }
        __syncthreads();
    }
    float4 bL = make_float4(0.f, 0.f, 0.f, 0.f), bH = bL;
    if (bias) {
        bL = *(const float4*)&bias[nt * 128 + tc * 4];
        bH = *(const float4*)&bias[nt * 128 + tc * 4 + 64];
    }
    #pragma unroll
    for (int ih = 0; ih < 2; ++ih)
        #pragma unroll
        for (int i2 = 0; i2 < 4; ++i2) {
            int i = ih * 4 + i2;
            int m = mt * 128 + ih * 64 + tr * 4 + i2;
            if (m < M) {
                float4 lo, hi;
                lo.x = acc[i][0] + bL.x; lo.y = acc[i][1] + bL.y;
                lo.z = acc[i][2] + bL.z; lo.w = acc[i][3] + bL.w;
                hi.x = acc[i][4] + bH.x; hi.y = acc[i][5] + bH.y;
                hi.z = acc[i][6] + bH.z; hi.w = acc[i][7] + bH.w;
                *(float4*)&C[(size_t)m * N + nt * 128 + tc * 4] = lo;
                *(float4*)&C[(size_t)m * N + nt * 128 + tc * 4 + 64] = hi;
            }
        }
}

// ---------------------------------------------------------------------------
// Step GEMMs: 16 rows x 128 cols per block, full-K register accumulation,
// K staged through LDS in 512-chunks, NO atomics.

// h = meanE@W_im + b_im ; c = meanE@W_ic + b_ic   (z-dim picks target)
__global__ __launch_bounds__(256) void k_initmc(
    const float* __restrict__ meanE, const float* __restrict__ Wim,
    const float* __restrict__ bim, const float* __restrict__ Wic,
    const float* __restrict__ bic, float* __restrict__ hB, float* __restrict__ cB)
{
    __shared__ float xs[16 * 512];
    int ry = blockIdx.y, ct = blockIdx.x;
    const float* W   = blockIdx.z ? Wic : Wim;
    const float* bia = blockIdx.z ? bic : bim;
    float* out       = blockIdx.z ? cB : hB;
    int ng = threadIdx.x & 31, rg = threadIdx.x >> 5;
    int col = ct * 128 + ng * 4;
    float acc[2][4] = {};
    for (int kc = 0; kc < 4; ++kc) {
        __syncthreads();
        for (int it = 0; it < 8; ++it) {
            int i4 = (it * 256 + threadIdx.x) * 4;
            int rr = i4 >> 9, k = i4 & 511;
            *(float4*)&xs[i4] =
                *(const float4*)&meanE[(size_t)(ry * 16 + rr) * EC + kc * 512 + k];
        }
        __syncthreads();
        const float* wp = W + (size_t)(kc * 512) * 512 + col;
        #pragma unroll 8
        for (int k = 0; k < 512; ++k) {
            float4 w = *(const float4*)(wp + (size_t)k * 512);
            float x0 = xs[(rg * 2) * 512 + k], x1 = xs[(rg * 2 + 1) * 512 + k];
            acc[0][0] += x0 * w.x; acc[0][1] += x0 * w.y; acc[0][2] += x0 * w.z; acc[0][3] += x0 * w.w;
            acc[1][0] += x1 * w.x; acc[1][1] += x1 * w.y; acc[1][2] += x1 * w.z; acc[1][3] += x1 * w.w;
        }
    }
    int r0 = ry * 16 + rg * 2;
    float4 bv = *(const float4*)&bia[col];
    float4 o0, o1;
    o0.x = acc[0][0] + bv.x; o0.y = acc[0][1] + bv.y; o0.z = acc[0][2] + bv.z; o0.w = acc[0][3] + bv.w;
    o1.x = acc[1][0] + bv.x; o1.y = acc[1][1] + bv.y; o1.z = acc[1][2] + bv.z; o1.w = acc[1][3] + bv.w;
    *(float4*)&out[(size_t)r0 * 512 + col] = o0;
    *(float4*)&out[(size_t)(r0 + 1) * 512 + col] = o1;
}

// att2 = c@W_ag + b_ag (ct<4) ; beta = c@W_b + b_b (ct>=4). K=512, direct store.
__global__ __launch_bounds__(256) void k_att2beta(
    const float* __restrict__ cB, const float* __restrict__ Wag,
    const float* __restrict__ bag, const float* __restrict__ Wb,
    const float* __restrict__ bb, float* __restrict__ att2B, float* __restrict__ betaB)
{
    __shared__ float xs[16 * 512];
    int ry = blockIdx.y, ct = blockIdx.x;   // ct 0..19
    const float* W; const float* bia; float* out; int N, colb;
    if (ct < 4) { W = Wag; bia = bag; out = att2B; N = 512;  colb = ct * 128; }
    else        { W = Wb;  bia = bb;  out = betaB; N = 2048; colb = (ct - 4) * 128; }
    int ng = threadIdx.x & 31, rg = threadIdx.x >> 5;
    int col = colb + ng * 4;
    for (int it = 0; it < 8; ++it) {
        int i4 = (it * 256 + threadIdx.x) * 4;
        int rr = i4 >> 9, k = i4 & 511;
        *(float4*)&xs[i4] = *(const float4*)&cB[(size_t)(ry * 16 + rr) * 512 + k];
    }
    __syncthreads();
    const float* wp = W + col;
    float acc[2][4] = {};
    #pragma unroll 8
    for (int k = 0; k < 512; ++k) {
        float4 w = *(const float4*)(wp + (size_t)k * N);
        float x0 = xs[(rg * 2) * 512 + k], x1 = xs[(rg * 2 + 1) * 512 + k];
        acc[0][0] += x0 * w.x; acc[0][1] += x0 * w.y; acc[0][2] += x0 * w.z; acc[0][3] += x0 * w.w;
        acc[1][0] += x1 * w.x; acc[1][1] += x1 * w.y; acc[1][2] += x1 * w.z; acc[1][3] += x1 * w.w;
    }
    int r0 = ry * 16 + rg * 2;
    float4 bv = *(const float4*)&bia[col];
    float4 o0, o1;
    o0.x = acc[0][0] + bv.x; o0.y = acc[0][1] + bv.y; o0.z = acc[0][2] + bv.z; o0.w = acc[0][3] + bv.w;
    o1.x = acc[1][0] + bv.x; o1.y = acc[1][1] + bv.y; o1.z = acc[1][2] + bv.z; o1.w = acc[1][3] + bv.w;
    *(float4*)&out[(size_t)r0 * N + col] = o0;
    *(float4*)&out[(size_t)(r0 + 1) * N + col] = o1;
}

// zP[kc] = (kc<4 ? awe[:,kc*512:+512] @ Wx2[kc] : h @ Wh).  Plain stores.
__global__ __launch_bounds__(256) void k_zgemm(
    const float* __restrict__ awe, const float* __restrict__ hB,
    const float* __restrict__ Wx2, const float* __restrict__ Wh,
    float* __restrict__ zP)
{
    __shared__ float xs[16 * 512];
    int kc = blockIdx.z, ry = blockIdx.y, ct = blockIdx.x;
    const float* xsrc; const float* W; int ldx;
    if (kc < 4) { xsrc = awe + kc * 512; ldx = EC;  W = Wx2 + (size_t)kc * 512 * EC; }
    else        { xsrc = hB;             ldx = 512; W = Wh; }
    int ng = threadIdx.x & 31, rg = threadIdx.x >> 5;
    int col = ct * 128 + ng * 4;
    for (int it = 0; it < 8; ++it) {
        int i4 = (it * 256 + threadIdx.x) * 4;
        int rr = i4 >> 9, k = i4 & 511;
        *(float4*)&xs[i4] = *(const float4*)&xsrc[(size_t)(ry * 16 + rr) * ldx + k];
    }
    __syncthreads();
    const float* wp = W + col;
    float acc[2][4] = {};
    #pragma unroll 8
    for (int k = 0; k < 512; ++k) {
        float4 w = *(const float4*)(wp + (size_t)k * EC);
        float x0 = xs[(rg * 2) * 512 + k], x1 = xs[(rg * 2 + 1) * 512 + k];
        acc[0][0] += x0 * w.x; acc[0][1] += x0 * w.y; acc[0][2] += x0 * w.z; acc[0][3] += x0 * w.w;
        acc[1][0] += x1 * w.x; acc[1][1] += x1 * w.y; acc[1][2] += x1 * w.z; acc[1][3] += x1 * w.w;
    }
    int r0 = ry * 16 + rg * 2;
    float* zp = zP + ((size_t)kc * 64 + r0) * EC + col;
    *(float4*)zp = *(float4*)acc[0];
    *(float4*)(zp + EC) = *(float4*)acc[1];
}

// logits = c @ W_out  (bias added in k_pred).  N=10000 with edge guards.
__global__ __launch_bounds__(256) void k_lgemm(
    const float* __restrict__ cB, const float* __restrict__ Wo,
    float* __restrict__ logit)
{
    __shared__ float xs[16 * 512];
    int ry = blockIdx.y, ct = blockIdx.x;   // ct 0..78
    int ng = threadIdx.x & 31, rg = threadIdx.x >> 5;
    int col = ct * 128 + ng * 4;
    for (int it = 0; it < 8; ++it) {
        int i4 = (it * 256 + threadIdx.x) * 4;
        int rr = i4 >> 9, k = i4 & 511;
        *(float4*)&xs[i4] = *(const float4*)&cB[(size_t)(ry * 16 + rr) * 512 + k];
    }
    __syncthreads();
    float acc[2][4] = {};
    bool full = (col + 4 <= VV);
    const float* wp = Wo + col;
    if (full) {
        #pragma unroll 8
        for (int k = 0; k < 512; ++k) {
            float4 w = *(const float4*)(wp + (size_t)k * VV);
            float x0 = xs[(rg * 2) * 512 + k], x1 = xs[(rg * 2 + 1) * 512 + k];
            acc[0][0] += x0 * w.x; acc[0][1] += x0 * w.y; acc[0][2] += x0 * w.z; acc[0][3] += x0 * w.w;
            acc[1][0] += x1 * w.x; acc[1][1] += x1 * w.y; acc[1][2] += x1 * w.z; acc[1][3] += x1 * w.w;
        }
    } else if (col < VV) {
        for (int k = 0; k < 512; ++k) {
            float x0 = xs[(rg * 2) * 512 + k], x1 = xs[(rg * 2 + 1) * 512 + k];
            #pragma unroll
            for (int j = 0; j < 4; ++j) {
                if (col + j < VV) {
                    float w = wp[(size_t)k * VV + j];
                    acc[0][j] += x0 * w; acc[1][j] += x1 * w;
                }
            }
        }
    }
    int r0 = ry * 16 + rg * 2;
    if (full) {
        *(float4*)&logit[(size_t)r0 * VV + col] = *(float4*)acc[0];
        *(float4*)&logit[(size_t)(r0 + 1) * VV + col] = *(float4*)acc[1];
    } else {
        for (int j = 0; j < 4; ++j)
            if (col + j < VV) {
                logit[(size_t)r0 * VV + col + j] = acc[0][j];
                logit[(size_t)(r0 + 1) * VV + col + j] = acc[1][j];
            }
    }
}

// ---------------------------------------------------------------------------
// e + softmax fused, one block per active batch row (b_ag pre-folded into att2).
__global__ __launch_bounds__(512) void k_score(
    const float* __restrict__ att1, const float* __restrict__ att2B,
    const float* __restrict__ Wf, const int* __restrict__ ilens,
    float* __restrict__ alphaS, float* __restrict__ out, int t)
{
    int b = blockIdx.x;
    if (t >= ilens[b]) return;
    __shared__ float att2g[AA], wfs[AA], es[PP], red[512];
    int tid = threadIdx.x;
    if (tid < AA) { att2g[tid] = att2B[b * AA + tid]; wfs[tid] = Wf[tid]; }
    __syncthreads();
    int wv = tid >> 6, lane = tid & 63;
    int a0 = lane * 8;
    float4 g0 = *(float4*)&att2g[a0], g1 = *(float4*)&att2g[a0 + 4];
    float4 w0 = *(float4*)&wfs[a0],  w1 = *(float4*)&wfs[a0 + 4];
    for (int p = wv; p < PP; p += 8) {
        const float4* A1 = (const float4*)(att1 + ((size_t)b * PP + p) * AA + a0);
        float4 x0 = A1[0], x1 = A1[1];
        float acc = fmaxf(x0.x + g0.x, 0.f) * w0.x + fmaxf(x0.y + g0.y, 0.f) * w0.y
                  + fmaxf(x0.z + g0.z, 0.f) * w0.z + fmaxf(x0.w + g0.w, 0.f) * w0.w
                  + fmaxf(x1.x + g1.x, 0.f) * w1.x + fmaxf(x1.y + g1.y, 0.f) * w1.y
                  + fmaxf(x1.z + g1.z, 0.f) * w1.z + fmaxf(x1.w + g1.w, 0.f) * w1.w;
        #pragma unroll
        for (int s = 32; s; s >>= 1) acc += __shfl_down(acc, s);
        if (lane == 0) es[p] = acc;
    }
    __syncthreads();
    float ev = (tid < PP) ? es[tid] : -1e30f;
    red[tid] = ev; __syncthreads();
    for (int s = 256; s >= 1; s >>= 1) {
        if (tid < s) red[tid] = fmaxf(red[tid], red[tid + s]);
        __syncthreads();
    }
    float mx = red[0]; __syncthreads();
    float ex = (tid < PP) ? expf(ev - mx) : 0.f;
    red[tid] = ex; __syncthreads();
    for (int s = 256; s >= 1; s >>= 1) {
        if (tid < s) red[tid] += red[tid + s];
        __syncthreads();
    }
    float inv = 1.0f / red[0];
    if (tid < PP) {
        float al = ex * inv;
        alphaS[b * PP + tid] = al;
        out[OUT_ALPHA + ((size_t)b * TT + t) * PP + tid] = al;
    }
}

// awe = (alpha . enc) * sigmoid(beta)   (b_b pre-folded into beta)
__global__ __launch_bounds__(256) void k_awe(
    const float* __restrict__ alphaS, const float* __restrict__ enc,
    const int* __restrict__ order, const int* __restrict__ ilens,
    const float* __restrict__ betaB, float* __restrict__ awe, int t)
{
    int b = blockIdx.y;
    if (t >= ilens[b]) return;
    int chunk = blockIdx.x, tid = threadIdx.x;
    __shared__ float al[PP];
    if (tid < PP) al[tid] = alphaS[b * PP + tid];
    __syncthreads();
    int e = chunk * 256 + tid;
    const float* ebase = enc + (size_t)order[b] * (PP * EC) + e;
    float s = 0.f;
    #pragma unroll 4
    for (int p = 0; p < PP; ++p) s += al[p] * ebase[(size_t)p * EC];
    awe[b * EC + e] = s * sigm(betaB[b * EC + e]);
}

// LSTM gates from 5 z-partials + zemb + bias; masked state update.
__global__ __launch_bounds__(256) void k_gates(
    const float* __restrict__ zP, const float* __restrict__ zemb,
    const float* __restrict__ blstm, float* __restrict__ h, float* __restrict__ c,
    const int* __restrict__ ilens, int t)
{
    int idx = blockIdx.x * 256 + threadIdx.x;   // b*512 + u
    int b = idx >> 9, u = idx & 511;
    if (t >= ilens[b]) return;
    const float* ze = zemb + ((size_t)b * TT + t) * EC;
    float g[4];
    #pragma unroll
    for (int j = 0; j < 4; ++j) {
        float s = ze[u + j * 512] + blstm[u + j * 512];
        #pragma unroll
        for (int kc = 0; kc < 5; ++kc)
            s += zP[((size_t)kc * 64 + b) * EC + u + j * 512];
        g[j] = s;
    }
    float cold = c[idx];
    float cn = sigm(g[1]) * cold + sigm(g[0]) * tanhf(g[2]);
    float hn = sigm(g[3]) * tanhf(cn);
    c[idx] = cn; h[idx] = hn;
}

// vocab softmax; logits in registers; active rows only.
__global__ __launch_bounds__(1024) void k_pred(
    const float* __restrict__ logits, const float* __restrict__ bout,
    const int* __restrict__ ilens, float* __restrict__ out, int t)
{
    int b = blockIdx.x;
    if (t >= ilens[b]) return;
    __shared__ float red[16];
    int tid = threadIdx.x;
    int lane = tid & 63, wv = tid >> 6;
    const float* lb = logits + (size_t)b * VV;
    float v[10];
    #pragma unroll
    for (int i = 0; i < 10; ++i) {
        int idx = tid + i * 1024;
        v[i] = (idx < VV) ? lb[idx] + bout[idx] : -1e30f;
    }
    float mx = v[0];
    #pragma unroll
    for (int i = 1; i < 10; ++i) mx = fmaxf(mx, v[i]);
    #pragma unroll
    for (int s = 32; s; s >>= 1) mx = fmaxf(mx, __shfl_xor(mx, s));
    if (lane == 0) red[wv] = mx;
    __syncthreads();
    if (tid == 0) {
        float m2 = red[0];
        for (int i = 1; i < 16; ++i) m2 = fmaxf(m2, red[i]);
        red[0] = m2;
    }
    __syncthreads();
    mx = red[0];
    __syncthreads();
    float sm = 0.f;
    #pragma unroll
    for (int i = 0; i < 10; ++i) {
        int idx = tid + i * 1024;
        float e = (idx < VV) ? expf(v[i] - mx) : 0.f;
        v[i] = e; sm += e;
    }
    #pragma unroll
    for (int s = 32; s; s >>= 1) sm += __shfl_xor(sm, s);
    if (lane == 0) red[wv] = sm;
    __syncthreads();
    if (tid == 0) {
        float s2 = 0.f;
        for (int i = 0; i < 16; ++i) s2 += red[i];
        red[0] = s2;
    }
    __syncthreads();
    float inv = 1.0f / red[0];
    float* po = out + OUT_PRED + ((size_t)b * TT + t) * VV;
    #pragma unroll
    for (int i = 0; i < 10; ++i) {
        int idx = tid + i * 1024;
        if (idx < VV) po[idx] = v[i] * inv;
    }
}

// ---------------------------------------------------------------------------
extern "C" void kernel_launch(void* const* d_in, const int* in_sizes, int n_in,
                              void* d_out, int out_size, void* d_ws, size_t ws_size,
                              hipStream_t stream)
{
    (void)in_sizes; (void)n_in; (void)out_size; (void)ws_size;
    const float* enc  = (const float*)d_in[0];
    const int*   seqs = (const int*)d_in[1];
    const int*   lens = (const int*)d_in[2];
    const float* embT = (const float*)d_in[3];
    const float* W_ae = (const float*)d_in[4];
    const float* b_ae = (const float*)d_in[5];
    const float* W_ag = (const float*)d_in[6];
    const float* b_ag = (const float*)d_in[7];
    const float* W_af = (const float*)d_in[8];
    // d_in[9] = b_att_full: constant pre-softmax shift, cancels.
    const float* W_x  = (const float*)d_in[10];
    const float* W_h  = (const float*)d_in[11];
    const float* b_l  = (const float*)d_in[12];
    const float* W_im = (const float*)d_in[13];
    const float* b_im = (const float*)d_in[14];
    const float* W_ic = (const float*)d_in[15];
    const float* b_ic = (const float*)d_in[16];
    const float* W_b  = (const float*)d_in[17];
    const float* b_b  = (const float*)d_in[18];
    const float* W_o  = (const float*)d_in[19];
    const float* b_o  = (const float*)d_in[20];
    float* out = (float*)d_out;

    float* ws     = (float*)d_ws;
    float* att1   = ws;                      // [B*P, A]    6422528
    float* zemb   = att1 + 6422528;          // [B*T, 4U]   2752512
    float* meanE  = zemb + 2752512;          // [B, ENC]    131072
    float* alphaS = meanE + 131072;          // [B, P]      12544
    float* aweB   = alphaS + 12544;          // [B, ENC]    131072
    float* att2B  = aweB + 131072;           // [B, A]      32768
    float* betaB  = att2B + 32768;           // [B, ENC]    131072
    float* hB     = betaB + 131072;          // [B, U]      32768
    float* cB     = hB + 32768;              // [B, U]      32768
    float* zP     = cB + 32768;              // [5][B, 4U]  655360
    float* logit  = zP + 655360;             // [B, V]      640000
    int* order = (int*)(logit + 640000);
    int* ilens = order + 64;
    int* roff1 = ilens + 64;                 // 12544
    int* roff2 = roff1 + 12544;              // 1344

    // masked outputs default to 0 (inactive rows are never written)
    hipMemsetAsync(out, 0, (size_t)OUT_SEQ * 4, stream);

    k_sort<<<1, 64, 0, stream>>>(lens, seqs, order, ilens, out);
    k_rowoff<<<49, 256, 0, stream>>>(order, seqs, roff1, roff2);
    k_mean<<<512, 256, 0, stream>>>(enc, order, meanE);
    k_initmc<<<dim3(4, 4, 2), 256, 0, stream>>>(meanE, W_im, b_im, W_ic, b_ic, hB, cB);

    // att1 = sorted_enc @ W_att_enc + b_att_enc   [12544 x 512], K=2048
    k_gemm_tile<<<98 * 4, 256, 0, stream>>>(enc, roff1, W_ae, b_ae, att1, 12544, 512, 2048);
    // zemb = emb(sorted tokens) @ W_x[0:512]      [1344 x 2048], K=512
    k_gemm_tile<<<11 * 16, 256, 0, stream>>>(embT, roff2, W_x, nullptr, zemb, 1344, 2048, 512);

    for (int t = 0; t < TT; ++t) {
        k_att2beta<<<dim3(20, 4), 256, 0, stream>>>(cB, W_ag, b_ag, W_b, b_b, att2B, betaB);
        k_score<<<64, 512, 0, stream>>>(att1, att2B, W_af, ilens, alphaS, out, t);
        k_awe<<<dim3(8, 64), 256, 0, stream>>>(alphaS, enc, order, ilens, betaB, aweB, t);
        k_zgemm<<<dim3(16, 4, 5), 256, 0, stream>>>(
            aweB, hB, W_x + (size_t)512 * 2048, W_h, zP);
        k_gates<<<128, 256, 0, stream>>>(zP, zemb, b_l, hB, cB, ilens, t);
        k_lgemm<<<dim3(79, 4), 256, 0, stream>>>(cB, W_o, logit);
        k_pred<<<64, 1024, 0, stream>>>(logit, b_o, ilens, out, t);
    }
}

// Round 5
// 2615.637 us; speedup vs baseline: 2.2179x; 1.4257x over previous
//
#include <hip/hip_runtime.h>
#include <math.h>

#define BB 64
#define PP 196
#define SS 22
#define TT 21
#define VV 10000
#define EE 512
#define AA 512
#define UU 512
#define EC 2048

// d_out layout (floats): pred [B,T,V] | alpha [B,T,P] | seqs [B,S] | iter_lens [B] | order [B]
#define OUT_PRED  0
#define OUT_ALPHA (BB*TT*VV)
#define OUT_SEQ   (OUT_ALPHA + BB*TT*PP)
#define OUT_ILEN  (OUT_SEQ + BB*SS)
#define OUT_ORDER (OUT_ILEN + BB)

__device__ __forceinline__ float sigm(float x) { return 1.0f / (1.0f + expf(-x)); }

// ---------------------------------------------------------------------------
__global__ void k_sort(const int* __restrict__ lens, const int* __restrict__ seqs,
                       int* __restrict__ order, int* __restrict__ ilens,
                       float* __restrict__ out)
{
    __shared__ int ord_s[BB];
    int i = threadIdx.x;
    int li = lens[i];
    int rank = 0;
    for (int j = 0; j < BB; ++j) {
        int lj = lens[j];
        rank += (lj > li) || (lj == li && j < i);
    }
    ord_s[rank] = i;
    __syncthreads();
    int o = ord_s[i];
    order[i] = o;
    int il = lens[o] - 1;
    ilens[i] = il;
    for (int s = 0; s < SS; ++s)
        out[OUT_SEQ + i * SS + s] = (float)seqs[o * SS + s];
    out[OUT_ILEN + i] = (float)il;
    out[OUT_ORDER + i] = (float)o;
}

__global__ void k_rowoff(const int* __restrict__ order, const int* __restrict__ seqs,
                         int* __restrict__ roff1, int* __restrict__ roff2)
{
    int idx = blockIdx.x * 256 + threadIdx.x;
    if (idx < BB * PP) {
        int b = idx / PP, p = idx % PP;
        roff1[idx] = order[b] * (PP * EC) + p * EC;
    }
    if (idx < BB * TT) {
        int b = idx / TT, t = idx % TT;
        int tok = seqs[order[b] * SS + t];
        roff2[idx] = tok * EE;
    }
}

__global__ __launch_bounds__(256) void k_mean(const float* __restrict__ enc,
                                              const int* __restrict__ order,
                                              float* __restrict__ meanE)
{
    int idx = blockIdx.x * 256 + threadIdx.x;   // b*2048 + e
    int b = idx >> 11, e = idx & 2047;
    const float* base = enc + (size_t)order[b] * (PP * EC) + e;
    float s = 0.f;
    for (int p = 0; p < PP; ++p) s += base[p * EC];
    meanE[idx] = s * (1.0f / PP);
}

// ---------------------------------------------------------------------------
// fp32 tile GEMM, gathered A rows (setup only: att1, zemb). Unchanged (r4).
__global__ __launch_bounds__(256) void k_gemm_tile(
    const float* __restrict__ Abase, const int* __restrict__ roff,
    const float* __restrict__ W, const float* __restrict__ bias,
    float* __restrict__ C, int M, int N, int K)
{
    __shared__ float As[16][128];
    __shared__ float Bs[16][128];
    int nwg = gridDim.x, bid = blockIdx.x;
    int q = nwg >> 3, r = nwg & 7;
    int x = bid & 7, y = bid >> 3;
    int lbid = (x < r ? x * (q + 1) : r * (q + 1) + (x - r) * q) + y;
    int ntn = N >> 7;
    int mt = lbid / ntn, nt = lbid % ntn;
    int tid = threadIdx.x;

    int arow = tid >> 1, akq = (tid & 1) * 8;
    int am = mt * 128 + arow; if (am > M - 1) am = M - 1;
    const float* aptr = Abase + (size_t)roff[am] + akq;
    int bkr = tid >> 5, bc4 = (tid & 31) * 4;
    const float* bptr = W + (size_t)bkr * N + nt * 128 + bc4;

    float4 a0 = *(const float4*)(aptr);
    float4 a1 = *(const float4*)(aptr + 4);
    float4 b0 = *(const float4*)(bptr);
    float4 b1 = *(const float4*)(bptr + (size_t)8 * N);

    int tr = tid >> 4, tc = tid & 15;
    float acc[8][8] = {};

    for (int k0 = 0; k0 < K; k0 += 16) {
        float* ac = &As[akq][arow];
        ac[0]   = a0.x; ac[128] = a0.y; ac[256] = a0.z; ac[384] = a0.w;
        ac[512] = a1.x; ac[640] = a1.y; ac[768] = a1.z; ac[896] = a1.w;
        *(float4*)&Bs[bkr][bc4] = b0;
        *(float4*)&Bs[bkr + 8][bc4] = b1;
        __syncthreads();
        if (k0 + 16 < K) {
            a0 = *(const float4*)(aptr + k0 + 16);
            a1 = *(const float4*)(aptr + k0 + 20);
            b0 = *(const float4*)(bptr + (size_t)(k0 + 16) * N);
            b1 = *(const float4*)(bptr + (size_t)(k0 + 24) * N);
        }
        #pragma unroll
        for (int kk = 0; kk < 16; ++kk) {
            float4 aL = *(float4*)&As[kk][tr * 4];
            float4 aH = *(float4*)&As[kk][tr * 4 + 64];
            float4 bL = *(float4*)&Bs[kk][tc * 4];
            float4 bH = *(float4*)&Bs[kk][tc * 4 + 64];
            float av[8] = {aL.x, aL.y, aL.z, aL.w, aH.x, aH.y, aH.z, aH.w};
            float bv[8] = {bL.x, bL.y, bL.z, bL.w, bH.x, bH.y, bH.z, bH.w};
            #pragma unroll
            for (int i = 0; i < 8; ++i)
                #pragma unroll
                for (int j = 0; j < 8; ++j)
                    acc[i][j] += av[i] * bv[j];
        }
        __syncthreads();
    }
    float4 bL = make_float4(0.f, 0.f, 0.f, 0.f), bH = bL;
    if (bias) {
        bL = *(const float4*)&bias[nt * 128 + tc * 4];
        bH = *(const float4*)&bias[nt * 128 + tc * 4 + 64];
    }
    #pragma unroll
    for (int ih = 0; ih < 2; ++ih)
        #pragma unroll
        for (int i2 = 0; i2 < 4; ++i2) {
            int i = ih * 4 + i2;
            int m = mt * 128 + ih * 64 + tr * 4 + i2;
            if (m < M) {
                float4 lo, hi;
                lo.x = acc[i][0] + bL.x; lo.y = acc[i][1] + bL.y;
                lo.z = acc[i][2] + bL.z; lo.w = acc[i][3] + bL.w;
                hi.x = acc[i][4] + bH.x; hi.y = acc[i][5] + bH.y;
                hi.z = acc[i][6] + bH.z; hi.w = acc[i][7] + bH.w;
                *(float4*)&C[(size_t)m * N + nt * 128 + tc * 4] = lo;
                *(float4*)&C[(size_t)m * N + nt * 128 + tc * 4 + 64] = hi;
            }
        }
}

// h = meanE@W_im + b_im ; c = meanE@W_ic + b_ic (z picks target). Setup-only.
__global__ __launch_bounds__(256) void k_initmc(
    const float* __restrict__ meanE, const float* __restrict__ Wim,
    const float* __restrict__ bim, const float* __restrict__ Wic,
    const float* __restrict__ bic, float* __restrict__ hB, float* __restrict__ cB)
{
    __shared__ float xs[16 * 512];
    int ry = blockIdx.y, ct = blockIdx.x;
    const float* W   = blockIdx.z ? Wic : Wim;
    const float* bia = blockIdx.z ? bic : bim;
    float* out       = blockIdx.z ? cB : hB;
    int ng = threadIdx.x & 31, rg = threadIdx.x >> 5;
    int col = ct * 128 + ng * 4;
    float acc[2][4] = {};
    for (int kc = 0; kc < 4; ++kc) {
        __syncthreads();
        for (int it = 0; it < 8; ++it) {
            int i4 = (it * 256 + threadIdx.x) * 4;
            int rr = i4 >> 9, k = i4 & 511;
            *(float4*)&xs[i4] =
                *(const float4*)&meanE[(size_t)(ry * 16 + rr) * EC + kc * 512 + k];
        }
        __syncthreads();
        const float* wp = W + (size_t)(kc * 512) * 512 + col;
        #pragma unroll 8
        for (int k = 0; k < 512; ++k) {
            float4 w = *(const float4*)(wp + (size_t)k * 512);
            float x0 = xs[(rg * 2) * 512 + k], x1 = xs[(rg * 2 + 1) * 512 + k];
            acc[0][0] += x0 * w.x; acc[0][1] += x0 * w.y; acc[0][2] += x0 * w.z; acc[0][3] += x0 * w.w;
            acc[1][0] += x1 * w.x; acc[1][1] += x1 * w.y; acc[1][2] += x1 * w.z; acc[1][3] += x1 * w.w;
        }
    }
    int r0 = ry * 16 + rg * 2;
    float4 bv = *(const float4*)&bia[col];
    float4 o0, o1;
    o0.x = acc[0][0] + bv.x; o0.y = acc[0][1] + bv.y; o0.z = acc[0][2] + bv.z; o0.w = acc[0][3] + bv.w;
    o1.x = acc[1][0] + bv.x; o1.y = acc[1][1] + bv.y; o1.z = acc[1][2] + bv.z; o1.w = acc[1][3] + bv.w;
    *(float4*)&out[(size_t)r0 * 512 + col] = o0;
    *(float4*)&out[(size_t)(r0 + 1) * 512 + col] = o1;
}

// ---------------------------------------------------------------------------
// Core step-GEMM building block: one block = ALL 64 batch rows x 128 cols x
// K=128 slice. Weights read exactly once across the grid (K-split partials,
// plain stores, row-guarded by ilens). x staged in LDS [64][132] (pad kills
// write conflicts; reads are 2-addr broadcasts).
__device__ __forceinline__ void mm64(
    float* __restrict__ xs,
    const float* __restrict__ x, int ldx, int kbase,
    const float* __restrict__ W, int ldw, int col0, int collim,
    float* __restrict__ dst, int ldd,
    int tcheck, const int* __restrict__ ilens)
{
    int tid = threadIdx.x;
    #pragma unroll
    for (int it = 0; it < 8; ++it) {
        int f4 = it * 256 + tid;
        int r = f4 >> 5, kf = (f4 & 31) * 4;
        *(float4*)&xs[r * 132 + kf] = *(const float4*)&x[(size_t)r * ldx + kbase + kf];
    }
    __syncthreads();
    int ng = tid & 31, rg = tid >> 5;         // 32 col-groups x 8 row-groups
    int col = col0 + ng * 4;
    if (col + 4 > collim) return;             // lgemm edge tile (collim % 4 == 0)
    float acc[8][4] = {};
    const float* wp = W + (size_t)kbase * ldw + col;
    #pragma unroll 4
    for (int k = 0; k < 128; ++k) {
        float4 w = *(const float4*)(wp + (size_t)k * ldw);
        #pragma unroll
        for (int i = 0; i < 8; ++i) {
            float xv = xs[(rg * 8 + i) * 132 + k];
            acc[i][0] += xv * w.x; acc[i][1] += xv * w.y;
            acc[i][2] += xv * w.z; acc[i][3] += xv * w.w;
        }
    }
    #pragma unroll
    for (int i = 0; i < 8; ++i) {
        int r = rg * 8 + i;
        if (tcheck < ilens[r])
            *(float4*)&dst[(size_t)r * ldd + col] = *(float4*)&acc[i][0];
    }
}

// att2/beta partials from c (80 blocks: 20 ct x 4 kz), used for step `tcheck`.
__device__ __forceinline__ void ab_part(
    float* xs, int b2, const float* cB, const float* Wag, const float* Wb,
    float* att2P, float* betaP, int tcheck, const int* ilens)
{
    int ct = b2 >> 2, kz = b2 & 3;
    if (ct < 4)
        mm64(xs, cB, 512, kz * 128, Wag, 512, ct * 128, 1 << 30,
             att2P + (size_t)kz * (BB * AA), 512, tcheck, ilens);
    else
        mm64(xs, cB, 512, kz * 128, Wb, 2048, (ct - 4) * 128, 1 << 30,
             betaP + (size_t)kz * (BB * EC), 2048, tcheck, ilens);
}

// pre-loop att2/beta for t=0
__global__ __launch_bounds__(256) void k_ab0(
    const float* __restrict__ cB, const float* __restrict__ Wag,
    const float* __restrict__ Wb, float* __restrict__ att2P,
    float* __restrict__ betaP, const int* __restrict__ ilens)
{
    __shared__ float xs[64 * 132];
    ab_part(xs, blockIdx.x, cB, Wag, Wb, att2P, betaP, 0, ilens);
}

// K1: logits(t) [316 blocks] U att2beta(t+1) [80 blocks]; both read new c.
__global__ __launch_bounds__(256) void k_fused1(
    const float* __restrict__ cB, const float* __restrict__ Wo,
    const float* __restrict__ Wag, const float* __restrict__ Wb,
    float* __restrict__ logitP, float* __restrict__ att2P,
    float* __restrict__ betaP, const int* __restrict__ ilens, int t)
{
    __shared__ float xs[64 * 132];
    int bid = blockIdx.x;
    if (bid < 316) {
        int ct = bid >> 2, kz = bid & 3;      // 79 ct x 4 kz, K=128
        mm64(xs, cB, 512, kz * 128, Wo, VV, ct * 128, VV,
             logitP + (size_t)kz * (BB * VV), VV, t, ilens);
    } else if (t + 1 < TT) {
        ab_part(xs, bid - 316, cB, Wag, Wb, att2P, betaP, t + 1, ilens);
    }
}

// K4: z partials (16 ct x 20 kz): kz<16 awe-slices @ Wx2, else h @ Wh.
__global__ __launch_bounds__(256) void k_zg(
    const float* __restrict__ aweB, const float* __restrict__ hB,
    const float* __restrict__ Wx2, const float* __restrict__ Wh,
    float* __restrict__ zP, const int* __restrict__ ilens, int t)
{
    __shared__ float xs[64 * 132];
    int ct = blockIdx.x, kz = blockIdx.y;
    if (kz < 16)
        mm64(xs, aweB, 2048, kz * 128, Wx2, 2048, ct * 128, 1 << 30,
             zP + (size_t)kz * (BB * EC), 2048, t, ilens);
    else
        mm64(xs, hB, 512, (kz - 16) * 128, Wh, 2048, ct * 128, 1 << 30,
             zP + (size_t)kz * (BB * EC), 2048, t, ilens);
}

// ---------------------------------------------------------------------------
// K2: score(t) [blocks 0..63] U pred(t-1) [blocks 64..127], 512 threads.
__global__ __launch_bounds__(512) void k_scorepred(
    const float* __restrict__ att1, const float* __restrict__ att2P,
    const float* __restrict__ bgen, const float* __restrict__ Wf,
    const float* __restrict__ logitP, const float* __restrict__ bout,
    const int* __restrict__ ilens, float* __restrict__ alphaS,
    float* __restrict__ out, int t)
{
    int tid = threadIdx.x;
    if (blockIdx.x < 64) {
        // ---- score ----
        int b = blockIdx.x;
        if (t >= TT || t >= ilens[b]) return;
        __shared__ float att2g[AA], wfs[AA], es[PP], red[512];
        att2g[tid] = att2P[b * AA + tid] + att2P[BB * AA + b * AA + tid]
                   + att2P[2 * BB * AA + b * AA + tid] + att2P[3 * BB * AA + b * AA + tid]
                   + bgen[tid];
        wfs[tid] = Wf[tid];
        __syncthreads();
        int wv = tid >> 6, lane = tid & 63;
        int a0 = lane * 8;
        float4 g0 = *(float4*)&att2g[a0], g1 = *(float4*)&att2g[a0 + 4];
        float4 w0 = *(float4*)&wfs[a0],  w1 = *(float4*)&wfs[a0 + 4];
        for (int p = wv; p < PP; p += 8) {
            const float4* A1 = (const float4*)(att1 + ((size_t)b * PP + p) * AA + a0);
            float4 x0 = A1[0], x1 = A1[1];
            float acc = fmaxf(x0.x + g0.x, 0.f) * w0.x + fmaxf(x0.y + g0.y, 0.f) * w0.y
                      + fmaxf(x0.z + g0.z, 0.f) * w0.z + fmaxf(x0.w + g0.w, 0.f) * w0.w
                      + fmaxf(x1.x + g1.x, 0.f) * w1.x + fmaxf(x1.y + g1.y, 0.f) * w1.y
                      + fmaxf(x1.z + g1.z, 0.f) * w1.z + fmaxf(x1.w + g1.w, 0.f) * w1.w;
            #pragma unroll
            for (int s = 32; s; s >>= 1) acc += __shfl_down(acc, s);
            if (lane == 0) es[p] = acc;
        }
        __syncthreads();
        float ev = (tid < PP) ? es[tid] : -1e30f;
        red[tid] = ev; __syncthreads();
        for (int s = 256; s >= 1; s >>= 1) {
            if (tid < s) red[tid] = fmaxf(red[tid], red[tid + s]);
            __syncthreads();
        }
        float mx = red[0]; __syncthreads();
        float ex = (tid < PP) ? expf(ev - mx) : 0.f;
        red[tid] = ex; __syncthreads();
        for (int s = 256; s >= 1; s >>= 1) {
            if (tid < s) red[tid] += red[tid + s];
            __syncthreads();
        }
        float inv = 1.0f / red[0];
        if (tid < PP) {
            float al = ex * inv;
            alphaS[b * PP + tid] = al;
            out[OUT_ALPHA + ((size_t)b * TT + t) * PP + tid] = al;
        }
    } else {
        // ---- pred for step t-1 ----
        int b = blockIdx.x - 64;
        int tp = t - 1;
        if (tp < 0 || tp >= ilens[b]) return;
        __shared__ float red8[8];
        int lane = tid & 63, wv = tid >> 6;
        const float* lb = logitP + (size_t)b * VV;
        float v[20];
        #pragma unroll
        for (int i = 0; i < 20; ++i) {
            int idx = tid + i * 512;
            if (idx < VV) {
                v[i] = lb[idx] + lb[BB * VV + idx] + lb[2 * BB * VV + idx]
                     + lb[3 * BB * VV + idx] + bout[idx];
            } else v[i] = -1e30f;
        }
        float mx = v[0];
        #pragma unroll
        for (int i = 1; i < 20; ++i) mx = fmaxf(mx, v[i]);
        #pragma unroll
        for (int s = 32; s; s >>= 1) mx = fmaxf(mx, __shfl_xor(mx, s));
        if (lane == 0) red8[wv] = mx;
        __syncthreads();
        if (tid == 0) {
            float m2 = red8[0];
            for (int i = 1; i < 8; ++i) m2 = fmaxf(m2, red8[i]);
            red8[0] = m2;
        }
        __syncthreads();
        mx = red8[0];
        __syncthreads();
        float sm = 0.f;
        #pragma unroll
        for (int i = 0; i < 20; ++i) {
            int idx = tid + i * 512;
            float e = (idx < VV) ? expf(v[i] - mx) : 0.f;
            v[i] = e; sm += e;
        }
        #pragma unroll
        for (int s = 32; s; s >>= 1) sm += __shfl_xor(sm, s);
        if (lane == 0) red8[wv] = sm;
        __syncthreads();
        if (tid == 0) {
            float s2 = 0.f;
            for (int i = 0; i < 8; ++i) s2 += red8[i];
            red8[0] = s2;
        }
        __syncthreads();
        float inv = 1.0f / red8[0];
        float* po = out + OUT_PRED + ((size_t)b * TT + tp) * VV;
        #pragma unroll
        for (int i = 0; i < 20; ++i) {
            int idx = tid + i * 512;
            if (idx < VV) po[idx] = v[i] * inv;
        }
    }
}

// awe = (alpha . enc) * sigmoid(sum betaP + b_b)
__global__ __launch_bounds__(256) void k_awe(
    const float* __restrict__ alphaS, const float* __restrict__ enc,
    const int* __restrict__ order, const int* __restrict__ ilens,
    const float* __restrict__ betaP, const float* __restrict__ bbeta,
    float* __restrict__ awe, int t)
{
    int b = blockIdx.y;
    if (t >= ilens[b]) return;
    int chunk = blockIdx.x, tid = threadIdx.x;
    __shared__ float al[PP];
    if (tid < PP) al[tid] = alphaS[b * PP + tid];
    __syncthreads();
    int e = chunk * 256 + tid;
    const float* ebase = enc + (size_t)order[b] * (PP * EC) + e;
    float s = 0.f;
    #pragma unroll 4
    for (int p = 0; p < PP; ++p) s += al[p] * ebase[(size_t)p * EC];
    float br = bbeta[e] + betaP[b * EC + e] + betaP[BB * EC + b * EC + e]
             + betaP[2 * BB * EC + b * EC + e] + betaP[3 * BB * EC + b * EC + e];
    awe[b * EC + e] = s * sigm(br);
}

// LSTM gates from 20 z-partials + zemb + bias; masked state update.
__global__ __launch_bounds__(256) void k_gates(
    const float* __restrict__ zP, const float* __restrict__ zemb,
    const float* __restrict__ blstm, float* __restrict__ h, float* __restrict__ c,
    const int* __restrict__ ilens, int t)
{
    int idx = blockIdx.x * 256 + threadIdx.x;   // b*512 + u
    int b = idx >> 9, u = idx & 511;
    if (t >= ilens[b]) return;
    const float* ze = zemb + ((size_t)b * TT + t) * EC;
    float g[4];
    #pragma unroll
    for (int j = 0; j < 4; ++j) {
        float s = ze[u + j * 512] + blstm[u + j * 512];
        #pragma unroll
        for (int kc = 0; kc < 20; ++kc)
            s += zP[(size_t)kc * (BB * EC) + b * EC + u + j * 512];
        g[j] = s;
    }
    float cold = c[idx];
    float cn = sigm(g[1]) * cold + sigm(g[0]) * tanhf(g[2]);
    float hn = sigm(g[3]) * tanhf(cn);
    c[idx] = cn; h[idx] = hn;
}

// ---------------------------------------------------------------------------
extern "C" void kernel_launch(void* const* d_in, const int* in_sizes, int n_in,
                              void* d_out, int out_size, void* d_ws, size_t ws_size,
                              hipStream_t stream)
{
    (void)in_sizes; (void)n_in; (void)out_size; (void)ws_size;
    const float* enc  = (const float*)d_in[0];
    const int*   seqs = (const int*)d_in[1];
    const int*   lens = (const int*)d_in[2];
    const float* embT = (const float*)d_in[3];
    const float* W_ae = (const float*)d_in[4];
    const float* b_ae = (const float*)d_in[5];
    const float* W_ag = (const float*)d_in[6];
    const float* b_ag = (const float*)d_in[7];
    const float* W_af = (const float*)d_in[8];
    // d_in[9] = b_att_full: constant pre-softmax shift, cancels.
    const float* W_x  = (const float*)d_in[10];
    const float* W_h  = (const float*)d_in[11];
    const float* b_l  = (const float*)d_in[12];
    const float* W_im = (const float*)d_in[13];
    const float* b_im = (const float*)d_in[14];
    const float* W_ic = (const float*)d_in[15];
    const float* b_ic = (const float*)d_in[16];
    const float* W_b  = (const float*)d_in[17];
    const float* b_b  = (const float*)d_in[18];
    const float* W_o  = (const float*)d_in[19];
    const float* b_o  = (const float*)d_in[20];
    float* out = (float*)d_out;

    // ws layout (floats). zP/logitP share one region (disjoint lifetimes:
    // zP live K4(t)->K5(t); logitP live K1(t)->K2(t+1)). meanE aliases att2P
    // (meanE dead after k_initmc, att2P first written by k_ab0 afterwards).
    float* ws     = (float*)d_ws;
    float* att1   = ws;                      // [B*P, A]         6,422,528
    float* zemb   = att1 + 6422528;          // [B*T, 4U]        2,752,512
    float* alphaS = zemb + 2752512;          // [B, P]              12,544
    float* aweB   = alphaS + 12544;          // [B, ENC]           131,072
    float* att2P  = aweB + 131072;           // [4][B, A]          131,072  (= meanE alias)
    float* betaP  = att2P + 131072;          // [4][B, ENC]        524,288
    float* hB     = betaP + 524288;          // [B, U]              32,768
    float* cB     = hB + 32768;              // [B, U]              32,768
    float* zlP    = cB + 32768;              // max(20 zP, 4 logitP) 2,621,440
    int* order = (int*)(zlP + 2621440);
    int* ilens = order + 64;
    int* roff1 = ilens + 64;                 // 12544
    int* roff2 = roff1 + 12544;              // 1344
    float* meanE  = att2P;                   // alias
    float* zP     = zlP;
    float* logitP = zlP;

    // masked outputs default to 0 (inactive rows never written)
    hipMemsetAsync(out, 0, (size_t)OUT_SEQ * 4, stream);

    k_sort<<<1, 64, 0, stream>>>(lens, seqs, order, ilens, out);
    k_rowoff<<<49, 256, 0, stream>>>(order, seqs, roff1, roff2);
    k_mean<<<512, 256, 0, stream>>>(enc, order, meanE);
    k_initmc<<<dim3(4, 4, 2), 256, 0, stream>>>(meanE, W_im, b_im, W_ic, b_ic, hB, cB);

    // att1 = sorted_enc @ W_att_enc + b_att_enc   [12544 x 512], K=2048
    k_gemm_tile<<<98 * 4, 256, 0, stream>>>(enc, roff1, W_ae, b_ae, att1, 12544, 512, 2048);
    // zemb = emb(sorted tokens) @ W_x[0:512]      [1344 x 2048], K=512
    k_gemm_tile<<<11 * 16, 256, 0, stream>>>(embT, roff2, W_x, nullptr, zemb, 1344, 2048, 512);

    // att2/beta for t=0
    k_ab0<<<80, 256, 0, stream>>>(cB, W_ag, W_b, att2P, betaP, ilens);

    const float* Wx2 = W_x + (size_t)512 * 2048;
    for (int t = 0; t < TT; ++t) {
        k_scorepred<<<128, 512, 0, stream>>>(
            att1, att2P, b_ag, W_af, logitP, b_o, ilens, alphaS, out, t);
        k_awe<<<dim3(8, 64), 256, 0, stream>>>(
            alphaS, enc, order, ilens, betaP, b_b, aweB, t);
        k_zg<<<dim3(16, 20), 256, 0, stream>>>(aweB, hB, Wx2, W_h, zP, ilens, t);
        k_gates<<<128, 256, 0, stream>>>(zP, zemb, b_l, hB, cB, ilens, t);
        k_fused1<<<396, 256, 0, stream>>>(
            cB, W_o, W_ag, W_b, logitP, att2P, betaP, ilens, t);
    }
    // final pred (t=20); score part self-disables at t=TT
    k_scorepred<<<128, 512, 0, stream>>>(
        att1, att2P, b_ag, W_af, logitP, b_o, ilens, alphaS, out, TT);
}